// Round 6
// baseline (363.403 us; speedup 1.0000x reference)
//
#include <hip/hip_runtime.h>
#include <hip/hip_bf16.h>

#define B 2
#define N 20000
#define M 4096
#define S 2
#define K 25
#define J 64
#define KJ (K*J)        // 1600
#define TC 32           // MLP column tile

#define GPB   128       // groups per block-pair (1 stage per block, 256 blocks)
#define NTH   1024      // 16 single-wave teams

typedef int   iv4 __attribute__((ext_vector_type(4)));
typedef float fv4 __attribute__((ext_vector_type(4)));

template<int CTRL>
__device__ __forceinline__ float dppadd(float x) {
    // x + value-from-partner-lane per DPP ctrl (all rows/banks, bound_ctrl=1)
    return x + __int_as_float(
        __builtin_amdgcn_update_dpp(0, __float_as_int(x), CTRL, 0xF, 0xF, true));
}
__device__ __forceinline__ float red8(float x) {
    x = dppadd<0xB1>(x);       // quad_perm xor1
    x = dppadd<0x4E>(x);       // quad_perm xor2
    x = dppadd<0x141>(x);      // row_half_mirror: q^7 completes 8-lane sum
    return x;
}

// ---------------- Kernel A: prep ----------------
// xf stored as TWO 8-byte channel planes per b: plane0 = c0..3 (x,y,f0,f1),
// plane1 = c4..7 (f2..f5). Each plane = 160000 B -> one whole plane fits LDS.
__global__ __launch_bounds__(256) void prep_kernel(
    const float* __restrict__ xyz, const float* __restrict__ feature,
    const float* __restrict__ new_xyz, const float* __restrict__ conv_w,
    const float* __restrict__ w0, const float* __restrict__ w1,
    __hip_bfloat16* __restrict__ xfh, float* __restrict__ conv_wT,
    float* __restrict__ w0T, float* __restrict__ w1T,
    float* __restrict__ wsum, float* __restrict__ out_newxyz) {
    const int T1 = B * N * 8;     // 320000
    const int T2 = 208 * 64;      // 13312 (52 float4-rows x 64 o)
    const int T3 = B * M * 3;     // 24576
    const int T4 = 128 * 128;     // 16384
    const int T5 = 128 * 256;     // 32768
    const int T6 = 128;           // wsum[c][o], c in {0,1}
    int e = blockIdx.x * blockDim.x + threadIdx.x;
    if (e < T1) {
        int r = e >> 3, t = e & 7;          // r = global row, t = channel
        int b = r / N, rr = r - b * N;
        int plane = t >> 2, tt = t & 3;
        float v = (t < 2) ? xyz[r * 3 + t] : feature[r * 6 + (t - 2)];
        xfh[((size_t)(b * 2 + plane) * N + rr) * 4 + tt] = __float2bfloat16(v);
    } else if (e < T1 + T2) {
        // float4-packed conv weights: cw4[i4][o][t], i = i4*4+t, i = k*8+c
        int e2 = e - T1;
        int i4 = e2 >> 8;          // [0,52)
        int rem = e2 & 255;
        int o = rem >> 2, t = rem & 3;
        int i = i4 * 4 + t;
        conv_wT[e2] = (i < 200) ? conv_w[o * 200 + (i & 7) * 25 + (i >> 3)] : 0.f;
    } else if (e < T1 + T2 + T3) {
        int e3 = e - T1 - T2;
        out_newxyz[e3] = new_xyz[e3];
    } else if (e < T1 + T2 + T3 + T4) {
        int e4 = e - T1 - T2 - T3;
        int c = e4 >> 7, o = e4 & 127;          // w0T[c][o]
        w0T[e4] = w0[o * 128 + c];
    } else if (e < T1 + T2 + T3 + T4 + T5) {
        int e5 = e - T1 - T2 - T3 - T4;
        int c = e5 >> 8, o = e5 & 255;          // w1T[c][o]
        w1T[e5] = w1[o * 128 + c];
    } else if (e < T1 + T2 + T3 + T4 + T5 + T6) {
        // center-correction weights: wsum[sel*64+o] = sum_k conv_w[o, sel, k]
        int e6 = e - T1 - T2 - T3 - T4 - T5;
        int o = e6 & 63, sel = e6 >> 6;
        float s = 0.f;
        for (int k = 0; k < 25; ++k) s += conv_w[o * 200 + sel * 25 + k];
        wsum[e6] = s;
    }
}

// ---------------- Kernel B: channel-split all-LDS gather, pipelined ----------------
// 256 blocks = 128 group-sets x 2 channel-planes, 1 block/CU, single stage.
// Whole 8B-row plane (20000 rows = 160000 B) in LDS; every gather is one
// unmasked ds_read_b64. Explicit 3-deep software pipeline: issue unit t+2's
// idx/weight nt-loads while processing unit t (16 units of (pass,u) per
// 4-group set, 2 sets per team) -- covers the ~600-900cy L2/HBM latency that
// r5's 52-VGPR serialized loads exposed at every pass boundary.
struct UD { iv4 ia, ib; fv4 wa, wb; };

__device__ __forceinline__ UD loadu(const int* __restrict__ idx,
                                    const float* __restrict__ weight,
                                    size_t base) {
    UD d;
    d.ia = __builtin_nontemporal_load((const iv4*)(idx + base));
    d.ib = __builtin_nontemporal_load((const iv4*)(idx + base) + 1);
    d.wa = __builtin_nontemporal_load((const fv4*)(weight + base));
    d.wb = __builtin_nontemporal_load((const fv4*)(weight + base) + 1);
    return d;
}

__device__ __forceinline__ void procu(const UD& d, const uint2* chunk, float* ar) {
    const int   ids[8] = {d.ia.x, d.ia.y, d.ia.z, d.ia.w, d.ib.x, d.ib.y, d.ib.z, d.ib.w};
    const float wsv[8] = {d.wa.x, d.wa.y, d.wa.z, d.wa.w, d.wb.x, d.wb.y, d.wb.z, d.wb.w};
    float a0 = 0.f, a1 = 0.f, a2 = 0.f, a3 = 0.f;
    #pragma unroll
    for (int j = 0; j < 8; ++j) {
        const uint2 v = chunk[ids[j]];
        const float w = wsv[j];
        a0 = fmaf(w, __uint_as_float(v.x << 16),         a0);
        a1 = fmaf(w, __uint_as_float(v.x & 0xffff0000u), a1);
        a2 = fmaf(w, __uint_as_float(v.y << 16),         a2);
        a3 = fmaf(w, __uint_as_float(v.y & 0xffff0000u), a3);
    }
    ar[0] = red8(a0); ar[1] = red8(a1); ar[2] = red8(a2); ar[3] = red8(a3);
}

template<int NK>
__device__ __forceinline__ void convp(const float4* __restrict__ wp,
                                      const float (*ar)[4], float* acc2) {
    #pragma unroll
    for (int kk = 0; kk < NK; ++kk) {
        const float4 w4 = wp[(size_t)kk * 128];
        #pragma unroll
        for (int u = 0; u < 4; ++u) {
            acc2[u] = fmaf(w4.x, __shfl(ar[u][0], kk * 8, 64), acc2[u]);
            acc2[u] = fmaf(w4.y, __shfl(ar[u][1], kk * 8, 64), acc2[u]);
            acc2[u] = fmaf(w4.z, __shfl(ar[u][2], kk * 8, 64), acc2[u]);
            acc2[u] = fmaf(w4.w, __shfl(ar[u][3], kk * 8, 64), acc2[u]);
        }
    }
}

__global__ __launch_bounds__(NTH, 4) void gather_conv_kernel(
    const int* __restrict__ idx, const float* __restrict__ weight,
    const float* __restrict__ new_xyz, const uint2* __restrict__ xfp,
    const float* __restrict__ conv_wT, const float* __restrict__ conv_b,
    const float* __restrict__ wsum,
    float* __restrict__ xmidA, float* __restrict__ xmidB) {
    __shared__ uint2 chunk[N];   // 160000 B

    const int bid   = blockIdx.x;
    const int plane = bid & 1;
    const int g0    = (bid >> 1) * GPB;        // 128 consecutive g: same (s,b)
    const int b     = (g0 >> 12) & (B - 1);
    const uint2* src = xfp + (size_t)(b * 2 + plane) * N;

    const int tid = threadIdx.x;
    for (int r = tid; r < N; r += NTH) chunk[r] = src[r];
    __syncthreads();

    const int team = tid >> 6;                 // 16 teams, one wave each
    const int lane = tid & 63;
    const float4* cw4 = (const float4*)conv_wT;
    const int cwo = plane * 64 + lane;         // plane0: c0..3, plane1: c4..7
    const int lg  = lane >> 3;
    const size_t joff = (size_t)((lane & 7) * 8);

    const float bo  = conv_b[lane];
    const float wsx = wsum[lane];
    const float wsy = wsum[64 + lane];

    // per-pass k value for this lane (pass 3 clamped to k=24, conv uses kk=0 only)
    const size_t mkJ0 = (size_t)(lg) * J;
    const size_t mkJ1 = (size_t)(8 + lg) * J;
    const size_t mkJ2 = (size_t)(16 + lg) * J;
    const size_t mkJ3 = (size_t)24 * J;

    #pragma unroll 1
    for (int set = 0; set < 2; ++set) {
        const int gbase = g0 + team * 8 + set * 4;
        const size_t gb = (size_t)gbase * KJ + joff;
        float acc2[4] = {0.f, 0.f, 0.f, 0.f};
        float ar[4][4];

        // 16 units t = p*4+u; issue t+2 while processing t (3-deep window)
        UD d0  = loadu(idx, weight, gb + 0 * KJ + mkJ0);
        UD d1  = loadu(idx, weight, gb + 1 * KJ + mkJ0);
        UD d2  = loadu(idx, weight, gb + 2 * KJ + mkJ0);  procu(d0,  chunk, ar[0]);
        UD d3  = loadu(idx, weight, gb + 3 * KJ + mkJ0);  procu(d1,  chunk, ar[1]);
        UD d4  = loadu(idx, weight, gb + 0 * KJ + mkJ1);  procu(d2,  chunk, ar[2]);
        UD d5  = loadu(idx, weight, gb + 1 * KJ + mkJ1);  procu(d3,  chunk, ar[3]);
        convp<8>(cw4 + (size_t)0 * 1024 + cwo, ar, acc2);
        UD d6  = loadu(idx, weight, gb + 2 * KJ + mkJ1);  procu(d4,  chunk, ar[0]);
        UD d7  = loadu(idx, weight, gb + 3 * KJ + mkJ1);  procu(d5,  chunk, ar[1]);
        UD d8  = loadu(idx, weight, gb + 0 * KJ + mkJ2);  procu(d6,  chunk, ar[2]);
        UD d9  = loadu(idx, weight, gb + 1 * KJ + mkJ2);  procu(d7,  chunk, ar[3]);
        convp<8>(cw4 + (size_t)1 * 1024 + cwo, ar, acc2);
        UD d10 = loadu(idx, weight, gb + 2 * KJ + mkJ2);  procu(d8,  chunk, ar[0]);
        UD d11 = loadu(idx, weight, gb + 3 * KJ + mkJ2);  procu(d9,  chunk, ar[1]);
        UD d12 = loadu(idx, weight, gb + 0 * KJ + mkJ3);  procu(d10, chunk, ar[2]);
        UD d13 = loadu(idx, weight, gb + 1 * KJ + mkJ3);  procu(d11, chunk, ar[3]);
        convp<8>(cw4 + (size_t)2 * 1024 + cwo, ar, acc2);
        UD d14 = loadu(idx, weight, gb + 2 * KJ + mkJ3);  procu(d12, chunk, ar[0]);
        UD d15 = loadu(idx, weight, gb + 3 * KJ + mkJ3);  procu(d13, chunk, ar[1]);
        procu(d14, chunk, ar[2]);
        procu(d15, chunk, ar[3]);
        convp<1>(cw4 + (size_t)3 * 1024 + cwo, ar, acc2);

        if (plane == 0) {
            #pragma unroll
            for (int u = 0; u < 4; ++u) {
                const int g = gbase + u;
                const int m = g & (M - 1);
                const int s = g >> 13;
                const float cx = new_xyz[(b * M + m) * 3 + 0];
                const float cy = new_xyz[(b * M + m) * 3 + 1];
                xmidA[((size_t)(b * M + m)) * 128 + s * 64 + lane]
                    = acc2[u] + bo - cx * wsx - cy * wsy;
            }
        } else {
            #pragma unroll
            for (int u = 0; u < 4; ++u) {
                const int g = gbase + u;
                const int m = g & (M - 1);
                const int s = g >> 13;
                xmidB[((size_t)(b * M + m)) * 128 + s * 64 + lane] = acc2[u];
            }
        }
    }
}

// ---------------- Kernel C: fused MLP0+MLP1 (h stays in LDS) ----------------
__device__ __forceinline__ void gemm_tile(const float* xs, const float* ws,
                                          int o0, int lc0, float acc[4][4]) {
    for (int c = 0; c < 128; ++c) {
        float4 xv = *(const float4*)&xs[c * 32 + lc0];
        float4 wv = *(const float4*)&ws[c * 128 + o0];
        acc[0][0] = fmaf(wv.x, xv.x, acc[0][0]);
        acc[0][1] = fmaf(wv.x, xv.y, acc[0][1]);
        acc[0][2] = fmaf(wv.x, xv.z, acc[0][2]);
        acc[0][3] = fmaf(wv.x, xv.w, acc[0][3]);
        acc[1][0] = fmaf(wv.y, xv.x, acc[1][0]);
        acc[1][1] = fmaf(wv.y, xv.y, acc[1][1]);
        acc[1][2] = fmaf(wv.y, xv.z, acc[1][2]);
        acc[1][3] = fmaf(wv.y, xv.w, acc[1][3]);
        acc[2][0] = fmaf(wv.z, xv.x, acc[2][0]);
        acc[2][1] = fmaf(wv.z, xv.y, acc[2][1]);
        acc[2][2] = fmaf(wv.z, xv.z, acc[2][2]);
        acc[2][3] = fmaf(wv.z, xv.w, acc[2][3]);
        acc[3][0] = fmaf(wv.w, xv.x, acc[3][0]);
        acc[3][1] = fmaf(wv.w, xv.y, acc[3][1]);
        acc[3][2] = fmaf(wv.w, xv.z, acc[3][2]);
        acc[3][3] = fmaf(wv.w, xv.w, acc[3][3]);
    }
}

__global__ __launch_bounds__(256) void mlp01_kernel(
    const float* __restrict__ xmidA, const float* __restrict__ xmidB,
    const float* __restrict__ w0T, const float* __restrict__ b0,
    const float* __restrict__ w1T, const float* __restrict__ b1,
    float* __restrict__ out_rf) {
    __shared__ float ws[128 * 128];   // 64 KB: w0, then w1-halfA, then w1-halfB
    __shared__ float xs[128 * 32];    // 16 KB: x, then h

    int tid = threadIdx.x;
    int col0 = blockIdx.x * TC;
    int og = tid >> 3, cg = tid & 7;
    int o0 = og * 4, lc0 = cg * 4;

    {
        const float4* w4 = (const float4*)w0T;
        float4* ws4 = (float4*)ws;
        #pragma unroll
        for (int i = 0; i < 16; ++i) ws4[tid + 256 * i] = w4[tid + 256 * i];
    }
    {
        const float4* xa4 = (const float4*)(xmidA + (size_t)col0 * 128);
        const float4* xb4 = (const float4*)(xmidB + (size_t)col0 * 128);
        #pragma unroll
        for (int r = tid; r < 1024; r += 256) {
            int lc = r >> 5, c4 = r & 31;
            float4 va = xa4[lc * 32 + c4];
            float4 vb = xb4[lc * 32 + c4];
            int c = c4 * 4;
            xs[(c + 0) * 32 + lc] = fmaxf(va.x + vb.x, 0.f);
            xs[(c + 1) * 32 + lc] = fmaxf(va.y + vb.y, 0.f);
            xs[(c + 2) * 32 + lc] = fmaxf(va.z + vb.z, 0.f);
            xs[(c + 3) * 32 + lc] = fmaxf(va.w + vb.w, 0.f);
        }
    }
    __syncthreads();

    // ---- MLP0 ----
    float acc[4][4];
    #pragma unroll
    for (int i = 0; i < 4; ++i) {
        float bv = b0[o0 + i];
        #pragma unroll
        for (int u = 0; u < 4; ++u) acc[i][u] = bv;
    }
    gemm_tile(xs, ws, o0, lc0, acc);
    __syncthreads();              // all xs(w0-input) + ws(w0) reads done

    // h -> xs (relu); w1 half A -> ws
    #pragma unroll
    for (int i = 0; i < 4; ++i)
        #pragma unroll
        for (int u = 0; u < 4; ++u)
            xs[(o0 + i) * 32 + lc0 + u] = fmaxf(acc[i][u], 0.f);
    for (int i = tid; i < 4096; i += 256) {
        int c = i >> 5, q = i & 31;
        *(float4*)&ws[c * 128 + q * 4] = *(const float4*)&w1T[c * 256 + q * 4];
    }
    __syncthreads();

    // ---- MLP1 half A (o 0..127) ----
    #pragma unroll
    for (int i = 0; i < 4; ++i) {
        float bv = b1[o0 + i];
        #pragma unroll
        for (int u = 0; u < 4; ++u) acc[i][u] = bv;
    }
    gemm_tile(xs, ws, o0, lc0, acc);
    #pragma unroll
    for (int u = 0; u < 4; ++u) {
        float4 v = make_float4(fmaxf(acc[0][u], 0.f), fmaxf(acc[1][u], 0.f),
                               fmaxf(acc[2][u], 0.f), fmaxf(acc[3][u], 0.f));
        *(float4*)&out_rf[(size_t)(col0 + lc0 + u) * 256 + o0] = v;
    }
    __syncthreads();              // ws(w1A) reads done

    for (int i = tid; i < 4096; i += 256) {
        int c = i >> 5, q = i & 31;
        *(float4*)&ws[c * 128 + q * 4] = *(const float4*)&w1T[c * 256 + 128 + q * 4];
    }
    __syncthreads();

    // ---- MLP1 half B (o 128..255) ----
    #pragma unroll
    for (int i = 0; i < 4; ++i) {
        float bv = b1[128 + o0 + i];
        #pragma unroll
        for (int u = 0; u < 4; ++u) acc[i][u] = bv;
    }
    gemm_tile(xs, ws, o0, lc0, acc);
    #pragma unroll
    for (int u = 0; u < 4; ++u) {
        float4 v = make_float4(fmaxf(acc[0][u], 0.f), fmaxf(acc[1][u], 0.f),
                               fmaxf(acc[2][u], 0.f), fmaxf(acc[3][u], 0.f));
        *(float4*)&out_rf[(size_t)(col0 + lc0 + u) * 256 + 128 + o0] = v;
    }
}

extern "C" void kernel_launch(void* const* d_in, const int* in_sizes, int n_in,
                              void* d_out, int out_size, void* d_ws, size_t ws_size,
                              hipStream_t stream) {
    const float* xyz     = (const float*)d_in[0];
    const float* feature = (const float*)d_in[1];
    const float* new_xyz = (const float*)d_in[2];
    const int*   idx     = (const int*)  d_in[3];
    const float* weight  = (const float*)d_in[4];
    const float* conv_w  = (const float*)d_in[5];
    const float* conv_b  = (const float*)d_in[6];
    const float* mlp_w0  = (const float*)d_in[7];
    const float* mlp_b0  = (const float*)d_in[8];
    const float* mlp_w1  = (const float*)d_in[9];
    const float* mlp_b1  = (const float*)d_in[10];

    float* out    = (float*)d_out;
    float* out_rf = out + (size_t)B * M * 3;

    float* wsf = (float*)d_ws;
    __hip_bfloat16* xfh = (__hip_bfloat16*)wsf;  // 320000 bf16 (2 planes x 2 b)
    float* conv_wT = wsf + 160000;               // 13312
    float* xmidA   = conv_wT + 13312;            // B*M*128, [col][c]
    float* w0T     = xmidA + 1048576;            // 16384
    float* w1T     = w0T + 16384;                // 32768
    float* wsum    = w1T + 32768;                // 128
    float* xmidB   = wsum + 128;                 // B*M*128 (plane-1 partials)

    {
        int total = 320000 + 13312 + 24576 + 16384 + 32768 + 128;
        int blocks = (total + 255) / 256;
        prep_kernel<<<blocks, 256, 0, stream>>>(xyz, feature, new_xyz, conv_w,
                                                mlp_w0, mlp_w1,
                                                xfh, conv_wT, w0T, w1T, wsum, out);
    }
    {
        int blocks = 2 * (S * B * M) / GPB;     // 256 = 128 group-sets x 2 planes
        gather_conv_kernel<<<blocks, NTH, 0, stream>>>(idx, weight, new_xyz,
                                                       (const uint2*)xfh,
                                                       conv_wT, conv_b, wsum,
                                                       xmidA, xmidB);
    }
    {
        mlp01_kernel<<<(B * M) / TC, 256, 0, stream>>>(xmidA, xmidB,
                                                       w0T, mlp_b0,
                                                       w1T, mlp_b1, out_rf);
    }
}

// Round 7
// 313.232 us; speedup vs baseline: 1.1602x; 1.1602x over previous
//
#include <hip/hip_runtime.h>
#include <hip/hip_bf16.h>

#define B 2
#define N 20000
#define M 4096
#define S 2
#define K 25
#define J 64
#define KJ (K*J)        // 1600
#define TC 32           // MLP column tile

#define GPB   128       // groups per block-pair (256 blocks, 1/CU, stage once)
#define NTH   1024      // 16 single-wave teams

typedef int   iv4 __attribute__((ext_vector_type(4)));
typedef float fv4 __attribute__((ext_vector_type(4)));

template<int CTRL>
__device__ __forceinline__ float dppadd(float x) {
    // x + value-from-partner-lane per DPP ctrl (all rows/banks, bound_ctrl=1)
    return x + __int_as_float(
        __builtin_amdgcn_update_dpp(0, __float_as_int(x), CTRL, 0xF, 0xF, true));
}
__device__ __forceinline__ float red8(float x) {
    x = dppadd<0xB1>(x);       // quad_perm xor1
    x = dppadd<0x4E>(x);       // quad_perm xor2
    x = dppadd<0x141>(x);      // row_half_mirror: q^7 completes 8-lane sum
    return x;
}
__device__ __forceinline__ float red16(float x) {
    x = dppadd<0xB1>(x);
    x = dppadd<0x4E>(x);
    x = dppadd<0x141>(x);
    x = dppadd<0x140>(x);      // row_mirror: q^15 completes 16-lane sum
    return x;
}
// broadcast from compile-time lane via v_readlane (VALU/SALU, no LDS pipe)
__device__ __forceinline__ float brd(float x, int l) {
    return __int_as_float(__builtin_amdgcn_readlane(__float_as_int(x), l));
}

// ---------------- Kernel A: prep ----------------
// xf stored as TWO 8-byte channel planes per b: plane0 = c0..3 (x,y,f0,f1),
// plane1 = c4..7 (f2..f5). Each plane = 160000 B -> one whole plane fits LDS.
__global__ __launch_bounds__(256) void prep_kernel(
    const float* __restrict__ xyz, const float* __restrict__ feature,
    const float* __restrict__ new_xyz, const float* __restrict__ conv_w,
    const float* __restrict__ w0, const float* __restrict__ w1,
    __hip_bfloat16* __restrict__ xfh, float* __restrict__ conv_wT,
    float* __restrict__ w0T, float* __restrict__ w1T,
    float* __restrict__ wsum, float* __restrict__ out_newxyz) {
    const int T1 = B * N * 8;     // 320000
    const int T2 = 208 * 64;      // 13312 (52 float4-rows x 64 o)
    const int T3 = B * M * 3;     // 24576
    const int T4 = 128 * 128;     // 16384
    const int T5 = 128 * 256;     // 32768
    const int T6 = 128;           // wsum[c][o], c in {0,1}
    int e = blockIdx.x * blockDim.x + threadIdx.x;
    if (e < T1) {
        int r = e >> 3, t = e & 7;          // r = global row, t = channel
        int b = r / N, rr = r - b * N;
        int plane = t >> 2, tt = t & 3;
        float v = (t < 2) ? xyz[r * 3 + t] : feature[r * 6 + (t - 2)];
        xfh[((size_t)(b * 2 + plane) * N + rr) * 4 + tt] = __float2bfloat16(v);
    } else if (e < T1 + T2) {
        // float4-packed conv weights: cw4[i4][o][t], i = i4*4+t, i = k*8+c
        int e2 = e - T1;
        int i4 = e2 >> 8;          // [0,52)
        int rem = e2 & 255;
        int o = rem >> 2, t = rem & 3;
        int i = i4 * 4 + t;
        conv_wT[e2] = (i < 200) ? conv_w[o * 200 + (i & 7) * 25 + (i >> 3)] : 0.f;
    } else if (e < T1 + T2 + T3) {
        int e3 = e - T1 - T2;
        out_newxyz[e3] = new_xyz[e3];
    } else if (e < T1 + T2 + T3 + T4) {
        int e4 = e - T1 - T2 - T3;
        int c = e4 >> 7, o = e4 & 127;          // w0T[c][o]
        w0T[e4] = w0[o * 128 + c];
    } else if (e < T1 + T2 + T3 + T4 + T5) {
        int e5 = e - T1 - T2 - T3 - T4;
        int c = e5 >> 8, o = e5 & 255;          // w1T[c][o]
        w1T[e5] = w1[o * 128 + c];
    } else if (e < T1 + T2 + T3 + T4 + T5 + T6) {
        // center-correction weights: wsum[sel*64+o] = sum_k conv_w[o, sel, k]
        int e6 = e - T1 - T2 - T3 - T4 - T5;
        int o = e6 & 63, sel = e6 >> 6;
        float s = 0.f;
        for (int k = 0; k < 25; ++k) s += conv_w[o * 200 + sel * 25 + k];
        wsum[e6] = s;
    }
}

// ---------------- Kernel B: channel-split all-LDS gather + half-conv ----------------
// 256 blocks = 128 group-sets x 2 channel-planes, 1 block/CU, staged ONCE.
// Whole 8B-row plane (20000 rows = 160000 B) in LDS; every gather is one
// unmasked ds_read_b64. Conv broadcast via v_readlane (VALU) instead of
// __shfl/ds_bpermute -- removes ~3.3M LDS-pipe ops + LDS latency from the
// acc2 chain (r5's hidden cost). Pass 3 (k=24) is a single zero-waste call:
// lane = (u=lane>>4, 4 j's), 16-lane DPP reduce -- kills r5's 7/8-wasted
// clamped pass (-19% gather work). Load scheduling left to the compiler
// (r5's proven 52-VGPR shape; r6's explicit 16-deep window spilled 100MB).
struct UD { iv4 ia, ib; fv4 wa, wb; };

__device__ __forceinline__ UD loadu(const int* __restrict__ idx,
                                    const float* __restrict__ weight,
                                    size_t base) {
    UD d;
    d.ia = __builtin_nontemporal_load((const iv4*)(idx + base));
    d.ib = __builtin_nontemporal_load((const iv4*)(idx + base) + 1);
    d.wa = __builtin_nontemporal_load((const fv4*)(weight + base));
    d.wb = __builtin_nontemporal_load((const fv4*)(weight + base) + 1);
    return d;
}

__device__ __forceinline__ void procu(const UD& d, const uint2* chunk, float* ar) {
    const int   ids[8] = {d.ia.x, d.ia.y, d.ia.z, d.ia.w, d.ib.x, d.ib.y, d.ib.z, d.ib.w};
    const float wsv[8] = {d.wa.x, d.wa.y, d.wa.z, d.wa.w, d.wb.x, d.wb.y, d.wb.z, d.wb.w};
    float a0 = 0.f, a1 = 0.f, a2 = 0.f, a3 = 0.f;
    #pragma unroll
    for (int j = 0; j < 8; ++j) {
        const uint2 v = chunk[ids[j]];
        const float w = wsv[j];
        a0 = fmaf(w, __uint_as_float(v.x << 16),         a0);
        a1 = fmaf(w, __uint_as_float(v.x & 0xffff0000u), a1);
        a2 = fmaf(w, __uint_as_float(v.y << 16),         a2);
        a3 = fmaf(w, __uint_as_float(v.y & 0xffff0000u), a3);
    }
    ar[0] = red8(a0); ar[1] = red8(a1); ar[2] = red8(a2); ar[3] = red8(a3);
}

__device__ __forceinline__ void convp8(const float4* __restrict__ wp,
                                       const float (*ar)[4], float* acc2) {
    #pragma unroll
    for (int kk = 0; kk < 8; ++kk) {
        const float4 w4 = wp[(size_t)kk * 128];
        #pragma unroll
        for (int u = 0; u < 4; ++u) {
            acc2[u] = fmaf(w4.x, brd(ar[u][0], kk * 8), acc2[u]);
            acc2[u] = fmaf(w4.y, brd(ar[u][1], kk * 8), acc2[u]);
            acc2[u] = fmaf(w4.z, brd(ar[u][2], kk * 8), acc2[u]);
            acc2[u] = fmaf(w4.w, brd(ar[u][3], kk * 8), acc2[u]);
        }
    }
}

__global__ __launch_bounds__(NTH, 4) void gather_conv_kernel(
    const int* __restrict__ idx, const float* __restrict__ weight,
    const float* __restrict__ new_xyz, const uint2* __restrict__ xfp,
    const float* __restrict__ conv_wT, const float* __restrict__ conv_b,
    const float* __restrict__ wsum,
    float* __restrict__ xmidA, float* __restrict__ xmidB) {
    __shared__ uint2 chunk[N];   // 160000 B

    const int bid   = blockIdx.x;
    const int plane = bid & 1;
    const int g0    = (bid >> 1) * GPB;        // 128 consecutive g: same (s,b)
    const int b     = (g0 >> 12) & (B - 1);
    const uint2* src = xfp + (size_t)(b * 2 + plane) * N;

    const int tid = threadIdx.x;
    for (int r = tid; r < N; r += NTH) chunk[r] = src[r];
    __syncthreads();

    const int team = tid >> 6;                 // 16 teams, one wave each
    const int lane = tid & 63;
    const float4* cw4 = (const float4*)conv_wT;
    const int cwo = plane * 64 + lane;         // plane0: c0..3, plane1: c4..7
    const int lg  = lane >> 3;
    const size_t joff = (size_t)((lane & 7) * 8);

    const float bo  = conv_b[lane];
    const float wsx = wsum[lane];
    const float wsy = wsum[64 + lane];

    #pragma unroll 1
    for (int set = 0; set < 2; ++set) {
        const int gbase = g0 + team * 8 + set * 4;
        float acc2[4] = {0.f, 0.f, 0.f, 0.f};
        float ar[4][4];

        // passes 0..2: k = p*8 + (lane>>3), 8 j's per lane -- zero waste
        #pragma unroll 1
        for (int p = 0; p < 3; ++p) {
            const size_t mkJ = (size_t)(p * 8 + lg) * J;
            #pragma unroll
            for (int u = 0; u < 4; ++u) {
                const size_t base = (size_t)(gbase + u) * KJ + mkJ + joff;
                UD d = loadu(idx, weight, base);
                procu(d, chunk, ar[u]);
            }
            convp8(cw4 + (size_t)(p * 8) * 128 + cwo, ar, acc2);
        }

        // pass 3 (k=24): all 4 u's in one call, lane = (u = lane>>4, 4 j's)
        {
            const int u16 = lane >> 4, sub = lane & 15;
            const size_t base3 = (size_t)(gbase + u16) * KJ + (size_t)24 * J + sub * 4;
            const iv4 i4v = __builtin_nontemporal_load((const iv4*)(idx + base3));
            const fv4 w4v = __builtin_nontemporal_load((const fv4*)(weight + base3));
            const int   ids3[4] = {i4v.x, i4v.y, i4v.z, i4v.w};
            const float ws3[4]  = {w4v.x, w4v.y, w4v.z, w4v.w};
            float a0 = 0.f, a1 = 0.f, a2 = 0.f, a3 = 0.f;
            #pragma unroll
            for (int j = 0; j < 4; ++j) {
                const uint2 v = chunk[ids3[j]];
                const float w = ws3[j];
                a0 = fmaf(w, __uint_as_float(v.x << 16),         a0);
                a1 = fmaf(w, __uint_as_float(v.x & 0xffff0000u), a1);
                a2 = fmaf(w, __uint_as_float(v.y << 16),         a2);
                a3 = fmaf(w, __uint_as_float(v.y & 0xffff0000u), a3);
            }
            a0 = red16(a0); a1 = red16(a1); a2 = red16(a2); a3 = red16(a3);
            const float4 wk = cw4[(size_t)24 * 128 + cwo];
            #pragma unroll
            for (int u = 0; u < 4; ++u) {
                acc2[u] = fmaf(wk.x, brd(a0, u * 16), acc2[u]);
                acc2[u] = fmaf(wk.y, brd(a1, u * 16), acc2[u]);
                acc2[u] = fmaf(wk.z, brd(a2, u * 16), acc2[u]);
                acc2[u] = fmaf(wk.w, brd(a3, u * 16), acc2[u]);
            }
        }

        if (plane == 0) {
            #pragma unroll
            for (int u = 0; u < 4; ++u) {
                const int g = gbase + u;
                const int m = g & (M - 1);
                const int s = g >> 13;
                const float cx = new_xyz[(b * M + m) * 3 + 0];
                const float cy = new_xyz[(b * M + m) * 3 + 1];
                xmidA[((size_t)(b * M + m)) * 128 + s * 64 + lane]
                    = acc2[u] + bo - cx * wsx - cy * wsy;
            }
        } else {
            #pragma unroll
            for (int u = 0; u < 4; ++u) {
                const int g = gbase + u;
                const int m = g & (M - 1);
                const int s = g >> 13;
                xmidB[((size_t)(b * M + m)) * 128 + s * 64 + lane] = acc2[u];
            }
        }
    }
}

// ---------------- Kernel C: fused MLP0+MLP1 (h stays in LDS) ----------------
__device__ __forceinline__ void gemm_tile(const float* xs, const float* ws,
                                          int o0, int lc0, float acc[4][4]) {
    for (int c = 0; c < 128; ++c) {
        float4 xv = *(const float4*)&xs[c * 32 + lc0];
        float4 wv = *(const float4*)&ws[c * 128 + o0];
        acc[0][0] = fmaf(wv.x, xv.x, acc[0][0]);
        acc[0][1] = fmaf(wv.x, xv.y, acc[0][1]);
        acc[0][2] = fmaf(wv.x, xv.z, acc[0][2]);
        acc[0][3] = fmaf(wv.x, xv.w, acc[0][3]);
        acc[1][0] = fmaf(wv.y, xv.x, acc[1][0]);
        acc[1][1] = fmaf(wv.y, xv.y, acc[1][1]);
        acc[1][2] = fmaf(wv.y, xv.z, acc[1][2]);
        acc[1][3] = fmaf(wv.y, xv.w, acc[1][3]);
        acc[2][0] = fmaf(wv.z, xv.x, acc[2][0]);
        acc[2][1] = fmaf(wv.z, xv.y, acc[2][1]);
        acc[2][2] = fmaf(wv.z, xv.z, acc[2][2]);
        acc[2][3] = fmaf(wv.z, xv.w, acc[2][3]);
        acc[3][0] = fmaf(wv.w, xv.x, acc[3][0]);
        acc[3][1] = fmaf(wv.w, xv.y, acc[3][1]);
        acc[3][2] = fmaf(wv.w, xv.z, acc[3][2]);
        acc[3][3] = fmaf(wv.w, xv.w, acc[3][3]);
    }
}

__global__ __launch_bounds__(256) void mlp01_kernel(
    const float* __restrict__ xmidA, const float* __restrict__ xmidB,
    const float* __restrict__ w0T, const float* __restrict__ b0,
    const float* __restrict__ w1T, const float* __restrict__ b1,
    float* __restrict__ out_rf) {
    __shared__ float ws[128 * 128];   // 64 KB: w0, then w1-halfA, then w1-halfB
    __shared__ float xs[128 * 32];    // 16 KB: x, then h

    int tid = threadIdx.x;
    int col0 = blockIdx.x * TC;
    int og = tid >> 3, cg = tid & 7;
    int o0 = og * 4, lc0 = cg * 4;

    {
        const float4* w4 = (const float4*)w0T;
        float4* ws4 = (float4*)ws;
        #pragma unroll
        for (int i = 0; i < 16; ++i) ws4[tid + 256 * i] = w4[tid + 256 * i];
    }
    {
        const float4* xa4 = (const float4*)(xmidA + (size_t)col0 * 128);
        const float4* xb4 = (const float4*)(xmidB + (size_t)col0 * 128);
        #pragma unroll
        for (int r = tid; r < 1024; r += 256) {
            int lc = r >> 5, c4 = r & 31;
            float4 va = xa4[lc * 32 + c4];
            float4 vb = xb4[lc * 32 + c4];
            int c = c4 * 4;
            xs[(c + 0) * 32 + lc] = fmaxf(va.x + vb.x, 0.f);
            xs[(c + 1) * 32 + lc] = fmaxf(va.y + vb.y, 0.f);
            xs[(c + 2) * 32 + lc] = fmaxf(va.z + vb.z, 0.f);
            xs[(c + 3) * 32 + lc] = fmaxf(va.w + vb.w, 0.f);
        }
    }
    __syncthreads();

    // ---- MLP0 ----
    float acc[4][4];
    #pragma unroll
    for (int i = 0; i < 4; ++i) {
        float bv = b0[o0 + i];
        #pragma unroll
        for (int u = 0; u < 4; ++u) acc[i][u] = bv;
    }
    gemm_tile(xs, ws, o0, lc0, acc);
    __syncthreads();              // all xs(w0-input) + ws(w0) reads done

    // h -> xs (relu); w1 half A -> ws
    #pragma unroll
    for (int i = 0; i < 4; ++i)
        #pragma unroll
        for (int u = 0; u < 4; ++u)
            xs[(o0 + i) * 32 + lc0 + u] = fmaxf(acc[i][u], 0.f);
    for (int i = tid; i < 4096; i += 256) {
        int c = i >> 5, q = i & 31;
        *(float4*)&ws[c * 128 + q * 4] = *(const float4*)&w1T[c * 256 + q * 4];
    }
    __syncthreads();

    // ---- MLP1 half A (o 0..127) ----
    #pragma unroll
    for (int i = 0; i < 4; ++i) {
        float bv = b1[o0 + i];
        #pragma unroll
        for (int u = 0; u < 4; ++u) acc[i][u] = bv;
    }
    gemm_tile(xs, ws, o0, lc0, acc);
    #pragma unroll
    for (int u = 0; u < 4; ++u) {
        float4 v = make_float4(fmaxf(acc[0][u], 0.f), fmaxf(acc[1][u], 0.f),
                               fmaxf(acc[2][u], 0.f), fmaxf(acc[3][u], 0.f));
        *(float4*)&out_rf[(size_t)(col0 + lc0 + u) * 256 + o0] = v;
    }
    __syncthreads();              // ws(w1A) reads done

    for (int i = tid; i < 4096; i += 256) {
        int c = i >> 5, q = i & 31;
        *(float4*)&ws[c * 128 + q * 4] = *(const float4*)&w1T[c * 256 + 128 + q * 4];
    }
    __syncthreads();

    // ---- MLP1 half B (o 128..255) ----
    #pragma unroll
    for (int i = 0; i < 4; ++i) {
        float bv = b1[128 + o0 + i];
        #pragma unroll
        for (int u = 0; u < 4; ++u) acc[i][u] = bv;
    }
    gemm_tile(xs, ws, o0, lc0, acc);
    #pragma unroll
    for (int u = 0; u < 4; ++u) {
        float4 v = make_float4(fmaxf(acc[0][u], 0.f), fmaxf(acc[1][u], 0.f),
                               fmaxf(acc[2][u], 0.f), fmaxf(acc[3][u], 0.f));
        *(float4*)&out_rf[(size_t)(col0 + lc0 + u) * 256 + 128 + o0] = v;
    }
}

extern "C" void kernel_launch(void* const* d_in, const int* in_sizes, int n_in,
                              void* d_out, int out_size, void* d_ws, size_t ws_size,
                              hipStream_t stream) {
    const float* xyz     = (const float*)d_in[0];
    const float* feature = (const float*)d_in[1];
    const float* new_xyz = (const float*)d_in[2];
    const int*   idx     = (const int*)  d_in[3];
    const float* weight  = (const float*)d_in[4];
    const float* conv_w  = (const float*)d_in[5];
    const float* conv_b  = (const float*)d_in[6];
    const float* mlp_w0  = (const float*)d_in[7];
    const float* mlp_b0  = (const float*)d_in[8];
    const float* mlp_w1  = (const float*)d_in[9];
    const float* mlp_b1  = (const float*)d_in[10];

    float* out    = (float*)d_out;
    float* out_rf = out + (size_t)B * M * 3;

    float* wsf = (float*)d_ws;
    __hip_bfloat16* xfh = (__hip_bfloat16*)wsf;  // 320000 bf16 (2 planes x 2 b)
    float* conv_wT = wsf + 160000;               // 13312
    float* xmidA   = conv_wT + 13312;            // B*M*128, [col][c]
    float* w0T     = xmidA + 1048576;            // 16384
    float* w1T     = w0T + 16384;                // 32768
    float* wsum    = w1T + 32768;                // 128
    float* xmidB   = wsum + 128;                 // B*M*128 (plane-1 partials)

    {
        int total = 320000 + 13312 + 24576 + 16384 + 32768 + 128;
        int blocks = (total + 255) / 256;
        prep_kernel<<<blocks, 256, 0, stream>>>(xyz, feature, new_xyz, conv_w,
                                                mlp_w0, mlp_w1,
                                                xfh, conv_wT, w0T, w1T, wsum, out);
    }
    {
        int blocks = 2 * (S * B * M) / GPB;     // 256 = 128 group-sets x 2 planes
        gather_conv_kernel<<<blocks, NTH, 0, stream>>>(idx, weight, new_xyz,
                                                       (const uint2*)xfh,
                                                       conv_wT, conv_b, wsum,
                                                       xmidA, xmidB);
    }
    {
        mlp01_kernel<<<(B * M) / TC, 256, 0, stream>>>(xmidA, xmidB,
                                                       w0T, mlp_b0,
                                                       w1T, mlp_b1, out_rf);
    }
}